// Round 1
// baseline (637.366 us; speedup 1.0000x reference)
//
#include <hip/hip_runtime.h>

// ---------------------------------------------------------------------------
// TapeHead: windowed chunk proj -> QKV -> MHA (H=16, full softmax) -> out proj
//           -> residual + LayerNorm.  B=4 S=2048 D=1024 C=2 H=16, M=B*S=8192.
// Round 0: correctness-first bf16 MFMA implementation (gemm_bt 64x64 tiles,
// flash attention with online softmax).
// ---------------------------------------------------------------------------

typedef __bf16 bf16x8 __attribute__((ext_vector_type(8)));
typedef float f32x4 __attribute__((ext_vector_type(4)));

__device__ __forceinline__ unsigned short f2bf(float x) {
  unsigned u = __float_as_uint(x);
  u += 0x7fffu + ((u >> 16) & 1u);
  return (unsigned short)(u >> 16);
}

// ---------------------------------------------------------------------------
// Build windowed A matrix in bf16: A_win[m][k], m=b*S+s, k in [0,2048):
//   k <  1024 -> emb[b][s][k]
//   k >= 1024 -> emb[b][s+1][k-1024]  (zeros when s == S-1)
// ---------------------------------------------------------------------------
__global__ __launch_bounds__(256) void build_awin(const float* __restrict__ emb,
                                                  ushort* __restrict__ aw) {
  const int i = blockIdx.x * 256 + threadIdx.x;   // one per 4 elems, 4M total
  const int e = i * 4;
  const int m = e >> 11;        // / 2048
  const int k = e & 2047;
  float4 v;
  if (k < 1024) {
    v = *(const float4*)(emb + (size_t)m * 1024 + k);
  } else {
    const int s = m & 2047;
    if (s == 2047) v = make_float4(0.f, 0.f, 0.f, 0.f);
    else           v = *(const float4*)(emb + (size_t)(m + 1) * 1024 + (k - 1024));
  }
  ushort4 o;
  o.x = f2bf(v.x); o.y = f2bf(v.y); o.z = f2bf(v.z); o.w = f2bf(v.w);
  *(ushort4*)(aw + (size_t)e) = o;
}

// Generic fp32 -> bf16 (n4 = count of float4 groups)
__global__ __launch_bounds__(256) void cvt_bf16(const float* __restrict__ in,
                                                ushort* __restrict__ out, int n4) {
  const int i = blockIdx.x * 256 + threadIdx.x;
  if (i >= n4) return;
  float4 v = ((const float4*)in)[i];
  ushort4 o;
  o.x = f2bf(v.x); o.y = f2bf(v.y); o.z = f2bf(v.z); o.w = f2bf(v.w);
  ((ushort4*)out)[i] = o;
}

// ---------------------------------------------------------------------------
// gemm_bt: C[m][n] = sum_k A[m][k] * W[n][k] + bias[n]   (A: MxK, W: NxK, both
// row-major bf16).  64x64 block tile, 4 waves, each wave 16 rows x 64 cols,
// mfma_f32_16x16x32_bf16.  Epilogue modes:
//   0: write fp32 (outf) + bf16 (outb), ld = N
//   1: qkv scatter -> q[b][h][s][64], k[b][h][s][64], vT[b][h][64][s]  (bf16)
//   2: outf = acc + bias + resid  (fp32)
// C/D layout (verified m89/m91): col = lane&15, row = (lane>>4)*4 + reg.
// A/B frag: row = lane&15 (m or n), k = (lane>>4)*8 + j  -> 8 contiguous bf16.
// ---------------------------------------------------------------------------
__global__ __launch_bounds__(256) void gemm_bt(
    const ushort* __restrict__ A, const ushort* __restrict__ W,
    const float* __restrict__ bias, int M, int N, int K, int mode,
    float* __restrict__ outf, ushort* __restrict__ outb,
    const float* __restrict__ resid,
    ushort* __restrict__ qp, ushort* __restrict__ kp, ushort* __restrict__ vtp) {
  __shared__ __align__(16) ushort sA[64][40];   // +8 pad: 80B row stride
  __shared__ __align__(16) ushort sB[64][40];
  const int m0 = blockIdx.y * 64, n0 = blockIdx.x * 64;
  const int t = threadIdx.x;
  const int wave = t >> 6, lane = t & 63;
  const int c16 = lane & 15, quad = lane >> 4;
  const int srow = t >> 2, scol = (t & 3) * 8;  // staging: 256 thr x 16B = 4KB tile
  f32x4 acc[4] = {{0.f, 0.f, 0.f, 0.f}, {0.f, 0.f, 0.f, 0.f},
                  {0.f, 0.f, 0.f, 0.f}, {0.f, 0.f, 0.f, 0.f}};
  for (int k0 = 0; k0 < K; k0 += 32) {
    __syncthreads();
    *(uint4*)&sA[srow][scol] = *(const uint4*)&A[(size_t)(m0 + srow) * K + k0 + scol];
    *(uint4*)&sB[srow][scol] = *(const uint4*)&W[(size_t)(n0 + srow) * K + k0 + scol];
    __syncthreads();
    bf16x8 af = *(const bf16x8*)&sA[wave * 16 + c16][quad * 8];
#pragma unroll
    for (int nt = 0; nt < 4; ++nt) {
      bf16x8 bfr = *(const bf16x8*)&sB[nt * 16 + c16][quad * 8];
      acc[nt] = __builtin_amdgcn_mfma_f32_16x16x32_bf16(af, bfr, acc[nt], 0, 0, 0);
    }
  }
#pragma unroll
  for (int nt = 0; nt < 4; ++nt) {
#pragma unroll
    for (int r = 0; r < 4; ++r) {
      const int m = m0 + wave * 16 + quad * 4 + r;
      const int n = n0 + nt * 16 + c16;
      float v = acc[nt][r] + bias[n];
      if (mode == 0) {
        outf[(size_t)m * N + n] = v;
        outb[(size_t)m * N + n] = f2bf(v);
      } else if (mode == 1) {
        const int sec = n >> 10, d = n & 1023, h = d >> 6, dd = d & 63;
        const int b = m >> 11, s = m & 2047;
        const unsigned short bv = f2bf(v);
        if (sec == 0)      qp[(((size_t)(b * 16 + h)) * 2048 + s) * 64 + dd] = bv;
        else if (sec == 1) kp[(((size_t)(b * 16 + h)) * 2048 + s) * 64 + dd] = bv;
        else               vtp[(((size_t)(b * 16 + h)) * 64 + dd) * 2048 + s] = bv;
      } else {
        outf[(size_t)m * N + n] = v + resid[(size_t)m * N + n];
      }
    }
  }
}

// ---------------------------------------------------------------------------
// Flash attention.  Grid (S/64, H, B), 256 threads = 4 waves; each wave owns
// 16 q-rows.  KV tiles of 64 keys.  q/k: [B][H][S][64] bf16, vT: [B][H][64][S].
// Output attn[b][s][h*64+d] bf16 (scattered 2B stores — fine for round 0).
// ---------------------------------------------------------------------------
__global__ __launch_bounds__(256) void attn_kernel(
    const ushort* __restrict__ qp, const ushort* __restrict__ kp,
    const ushort* __restrict__ vtp, ushort* __restrict__ attn_out) {
  const int S = 2048, H = 16;
  const int qblk = blockIdx.x, h = blockIdx.y, b = blockIdx.z;
  const int t = threadIdx.x, wave = t >> 6, lane = t & 63;
  const int c16 = lane & 15, quad = lane >> 4;
  __shared__ __align__(16) ushort sK[64][72];       // [key][d]
  __shared__ __align__(16) ushort sV[64][72];       // [d][key]  (V^T)
  __shared__ __align__(16) ushort sP[4][16][72];    // per-wave [qrow][key]
  const size_t headq = (size_t)(b * H + h) * S;     // row base (x64 elems) q/k
  const size_t headv = (size_t)(b * H + h) * 64;    // row base (xS elems) vT
  const int q0 = qblk * 64;

  bf16x8 qf0, qf1;
  {
    const ushort* qrow = qp + (headq + q0 + wave * 16 + c16) * 64;
    qf0 = *(const bf16x8*)&qrow[quad * 8];
    qf1 = *(const bf16x8*)&qrow[32 + quad * 8];
  }
  f32x4 o[4] = {{0.f, 0.f, 0.f, 0.f}, {0.f, 0.f, 0.f, 0.f},
                {0.f, 0.f, 0.f, 0.f}, {0.f, 0.f, 0.f, 0.f}};
  float mi[4], li[4];
#pragma unroll
  for (int r = 0; r < 4; ++r) { mi[r] = -1e30f; li[r] = 0.f; }
  const float scale = 0.125f;  // 1/sqrt(64)

  for (int kv0 = 0; kv0 < S; kv0 += 64) {
    __syncthreads();
    {  // stage K tile (contiguous 8KB) and V^T tile (64 rows x 128B)
      const uint4* src = (const uint4*)(kp + (headq + kv0) * 64);
#pragma unroll
      for (int i = 0; i < 2; ++i) {
        const int idx = t + i * 256;          // 0..511
        const int row = idx >> 3, c8 = (idx & 7) * 8;
        *(uint4*)&sK[row][c8] = src[idx];
        *(uint4*)&sV[row][c8] = *(const uint4*)(vtp + (headv + row) * S + kv0 + c8);
      }
    }
    __syncthreads();
    // S-tile = Q K^T  (16 q-rows x 64 keys per wave)
    f32x4 sacc[4];
#pragma unroll
    for (int nt = 0; nt < 4; ++nt) {
      f32x4 z = {0.f, 0.f, 0.f, 0.f};
      bf16x8 k0f = *(const bf16x8*)&sK[nt * 16 + c16][quad * 8];
      bf16x8 k1f = *(const bf16x8*)&sK[nt * 16 + c16][32 + quad * 8];
      z = __builtin_amdgcn_mfma_f32_16x16x32_bf16(qf0, k0f, z, 0, 0, 0);
      z = __builtin_amdgcn_mfma_f32_16x16x32_bf16(qf1, k1f, z, 0, 0, 0);
      sacc[nt] = z;
    }
    // online softmax; row r of this wave's 16 lives in lanes with this quad,
    // reg r; stats reduce across the 16 lanes of the quad group.
    float mnew[4], alpha[4], rsum[4];
#pragma unroll
    for (int r = 0; r < 4; ++r) {
      float mx = fmaxf(fmaxf(sacc[0][r], sacc[1][r]), fmaxf(sacc[2][r], sacc[3][r]));
      mx *= scale;
#pragma unroll
      for (int off = 1; off < 16; off <<= 1) mx = fmaxf(mx, __shfl_xor(mx, off, 64));
      mnew[r] = fmaxf(mi[r], mx);
      alpha[r] = __expf(mi[r] - mnew[r]);
      rsum[r] = 0.f;
    }
#pragma unroll
    for (int nt = 0; nt < 4; ++nt) {
#pragma unroll
      for (int r = 0; r < 4; ++r) {
        const float p = __expf(sacc[nt][r] * scale - mnew[r]);
        rsum[r] += p;
        sP[wave][quad * 4 + r][nt * 16 + c16] = f2bf(p);
      }
    }
#pragma unroll
    for (int r = 0; r < 4; ++r) {
#pragma unroll
      for (int off = 1; off < 16; off <<= 1) rsum[r] += __shfl_xor(rsum[r], off, 64);
      li[r] = li[r] * alpha[r] + rsum[r];
      mi[r] = mnew[r];
    }
#pragma unroll
    for (int nt = 0; nt < 4; ++nt)
#pragma unroll
      for (int r = 0; r < 4; ++r) o[nt][r] *= alpha[r];
    __syncthreads();  // safety: sP writes visible before A-frag reads
    // O += P V   (P: 16x64 A-layout from sP; V via sV = V^T, bt-form)
    bf16x8 pf0 = *(const bf16x8*)&sP[wave][c16][quad * 8];
    bf16x8 pf1 = *(const bf16x8*)&sP[wave][c16][32 + quad * 8];
#pragma unroll
    for (int nt = 0; nt < 4; ++nt) {
      bf16x8 v0f = *(const bf16x8*)&sV[nt * 16 + c16][quad * 8];
      bf16x8 v1f = *(const bf16x8*)&sV[nt * 16 + c16][32 + quad * 8];
      o[nt] = __builtin_amdgcn_mfma_f32_16x16x32_bf16(pf0, v0f, o[nt], 0, 0, 0);
      o[nt] = __builtin_amdgcn_mfma_f32_16x16x32_bf16(pf1, v1f, o[nt], 0, 0, 0);
    }
  }
  // epilogue: attn[b][s][h*64+d]
#pragma unroll
  for (int nt = 0; nt < 4; ++nt) {
#pragma unroll
    for (int r = 0; r < 4; ++r) {
      const int s = q0 + wave * 16 + quad * 4 + r;
      const int d = h * 64 + nt * 16 + c16;
      attn_out[((size_t)(b * S + s)) * 1024 + d] = f2bf(o[nt][r] / li[r]);
    }
  }
}

// ---------------------------------------------------------------------------
// LayerNorm over D=1024 per row; one block per row.
// ---------------------------------------------------------------------------
__global__ __launch_bounds__(256) void ln_kernel(const float* __restrict__ y,
                                                 const float* __restrict__ g,
                                                 const float* __restrict__ bta,
                                                 float* __restrict__ out) {
  const int m = blockIdx.x;
  const int t = threadIdx.x;
  const float* row = y + (size_t)m * 1024;
  float4 v = ((const float4*)row)[t];
  float s = v.x + v.y + v.z + v.w;
  float s2 = v.x * v.x + v.y * v.y + v.z * v.z + v.w * v.w;
#pragma unroll
  for (int off = 1; off < 64; off <<= 1) {
    s += __shfl_xor(s, off, 64);
    s2 += __shfl_xor(s2, off, 64);
  }
  __shared__ float red[8];
  const int wave = t >> 6, lane = t & 63;
  if (lane == 0) { red[wave] = s; red[4 + wave] = s2; }
  __syncthreads();
  s = red[0] + red[1] + red[2] + red[3];
  s2 = red[4] + red[5] + red[6] + red[7];
  const float mu = s * (1.f / 1024.f);
  const float var = s2 * (1.f / 1024.f) - mu * mu;
  const float rs = rsqrtf(var + 1e-5f);
  float4 gg = ((const float4*)g)[t];
  float4 bb = ((const float4*)bta)[t];
  float4 o;
  o.x = (v.x - mu) * rs * gg.x + bb.x;
  o.y = (v.y - mu) * rs * gg.y + bb.y;
  o.z = (v.z - mu) * rs * gg.z + bb.z;
  o.w = (v.w - mu) * rs * gg.w + bb.w;
  ((float4*)(out + (size_t)m * 1024))[t] = o;
}

// ---------------------------------------------------------------------------
// Workspace layout (bytes; peak ~140 MB):
//   [0,32M)    A_win bf16 (8192x2048)         -- reused as y fp32 in phase 5
//   [32,64M)   chunk fp32 (8192x1024)
//   [64,80M)   chunk bf16 -> later attn bf16  (8192x1024)
//   [80,96M)   q bf16  [B][H][S][64]
//   [96,112M)  k bf16  [B][H][S][64]
//   [112,128M) vT bf16 [B][H][64][S]
//   [128,132M) chunk_w bf16   [132,138M) in_proj_w bf16   [138,140M) out_proj_w bf16
// ---------------------------------------------------------------------------
extern "C" void kernel_launch(void* const* d_in, const int* in_sizes, int n_in,
                              void* d_out, int out_size, void* d_ws, size_t ws_size,
                              hipStream_t stream) {
  const float* emb        = (const float*)d_in[0];
  const float* chunk_w    = (const float*)d_in[1];
  const float* chunk_b    = (const float*)d_in[2];
  const float* in_proj_w  = (const float*)d_in[3];
  const float* in_proj_b  = (const float*)d_in[4];
  const float* out_proj_w = (const float*)d_in[5];
  const float* out_proj_b = (const float*)d_in[6];
  const float* ln_g       = (const float*)d_in[7];
  const float* ln_b       = (const float*)d_in[8];
  // d_in[9] = num_heads (16), compile-time constant here.

  char* w = (char*)d_ws;
  const size_t MBy = (size_t)1 << 20;
  ushort* awin   = (ushort*)(w + 0);
  float*  y      = (float*)(w + 0);            // aliases awin (dead by then)
  float*  chunkf = (float*)(w + 32 * MBy);
  ushort* chunkb = (ushort*)(w + 64 * MBy);
  ushort* attnb  = (ushort*)(w + 64 * MBy);    // aliases chunkb (dead by then)
  ushort* qb     = (ushort*)(w + 80 * MBy);
  ushort* kb     = (ushort*)(w + 96 * MBy);
  ushort* vtb    = (ushort*)(w + 112 * MBy);
  ushort* cwb    = (ushort*)(w + 128 * MBy);
  ushort* ipwb   = (ushort*)(w + 132 * MBy);
  ushort* opwb   = (ushort*)(w + 138 * MBy);

  // Phase 1: bf16 conversions
  build_awin<<<16384, 256, 0, stream>>>(emb, awin);                 // 8192*2048/4 threads
  cvt_bf16<<<2048, 256, 0, stream>>>(chunk_w, cwb, 2 * 1024 * 1024 / 4);
  cvt_bf16<<<3072, 256, 0, stream>>>(in_proj_w, ipwb, 3 * 1024 * 1024 / 4);
  cvt_bf16<<<1024, 256, 0, stream>>>(out_proj_w, opwb, 1024 * 1024 / 4);

  // Phase 2: chunk = A_win @ chunk_w^T + b   (M=8192 N=1024 K=2048)
  gemm_bt<<<dim3(1024 / 64, 8192 / 64), 256, 0, stream>>>(
      awin, cwb, chunk_b, 8192, 1024, 2048, 0,
      chunkf, chunkb, nullptr, nullptr, nullptr, nullptr);

  // Phase 3: qkv = chunk @ in_proj_w^T + b   (N=3072 K=1024) -> q/k/vT scatter
  gemm_bt<<<dim3(3072 / 64, 8192 / 64), 256, 0, stream>>>(
      chunkb, ipwb, in_proj_b, 8192, 3072, 1024, 1,
      nullptr, nullptr, nullptr, qb, kb, vtb);

  // Phase 4: attention
  attn_kernel<<<dim3(2048 / 64, 16, 4), 256, 0, stream>>>(qb, kb, vtb, attnb);

  // Phase 5: y = attn @ out_proj_w^T + b + chunk   (N=1024 K=1024)
  gemm_bt<<<dim3(1024 / 64, 8192 / 64), 256, 0, stream>>>(
      attnb, opwb, out_proj_b, 8192, 1024, 1024, 2,
      y, nullptr, chunkf, nullptr, nullptr, nullptr);

  // Phase 6: LayerNorm -> d_out
  ln_kernel<<<8192, 256, 0, stream>>>(y, ln_g, ln_b, (float*)d_out);
}

// Round 3
// 512.953 us; speedup vs baseline: 1.2425x; 1.2425x over previous
//
#include <hip/hip_runtime.h>

// ---------------------------------------------------------------------------
// TapeHead R3: windowed chunk proj -> QKV -> MHA -> out proj -> LN.
// B=4 S=2048 D=1024 C=2 H=16, M=8192.
// GEMMs: m97-style 128x128 tiles + global_load_lds(16B) + plane LDS layout.
// Attention: 32x32x16 MFMA, KV=128, S^T=K.Q^T / O^T=V^T.P orientation
// (lane-local softmax stats), swizzled LDS (64KB), exp2-domain softmax.
// R3 fix: vtrans loaded only half its 64x64 tile (rows 0..31); rows 32..63
// were stale LDS -> NaN bf16 patterns in V^T. Now loads both halves.
// ---------------------------------------------------------------------------

typedef __bf16 bf16x8 __attribute__((ext_vector_type(8)));
typedef float f32x4 __attribute__((ext_vector_type(4)));
typedef float f32x16 __attribute__((ext_vector_type(16)));

#if __has_builtin(__builtin_amdgcn_exp2f)
#define EXP2(x) __builtin_amdgcn_exp2f(x)
#else
#define EXP2(x) exp2f(x)
#endif

__device__ __forceinline__ unsigned short f2bf(float x) {
  unsigned u = __float_as_uint(x);
  u += 0x7fffu + ((u >> 16) & 1u);
  return (unsigned short)(u >> 16);
}

// async global->LDS, 16B per lane; LDS dest = base + lane*16 (wave-uniform base)
__device__ __forceinline__ void glds16(const ushort* g, ushort* l) {
  __builtin_amdgcn_global_load_lds(
      (const __attribute__((address_space(1))) unsigned int*)g,
      (__attribute__((address_space(3))) unsigned int*)l, 16, 0, 0);
}

// ---------------------------------------------------------------------------
// Build windowed A: A_win[m][k], k<1024 -> emb[m][k]; k>=1024 -> emb[m+1][k-1024]
// (zeros when s==S-1).
// ---------------------------------------------------------------------------
__global__ __launch_bounds__(256) void build_awin(const float* __restrict__ emb,
                                                  ushort* __restrict__ aw) {
  const int i = blockIdx.x * 256 + threadIdx.x;
  const int e = i * 4;
  const int m = e >> 11;
  const int k = e & 2047;
  float4 v;
  if (k < 1024) {
    v = *(const float4*)(emb + (size_t)m * 1024 + k);
  } else {
    const int s = m & 2047;
    if (s == 2047) v = make_float4(0.f, 0.f, 0.f, 0.f);
    else           v = *(const float4*)(emb + (size_t)(m + 1) * 1024 + (k - 1024));
  }
  ushort4 o;
  o.x = f2bf(v.x); o.y = f2bf(v.y); o.z = f2bf(v.z); o.w = f2bf(v.w);
  *(ushort4*)(aw + (size_t)e) = o;
}

__global__ __launch_bounds__(256) void cvt_bf16(const float* __restrict__ in,
                                                ushort* __restrict__ out, int n4) {
  const int i = blockIdx.x * 256 + threadIdx.x;
  if (i >= n4) return;
  float4 v = ((const float4*)in)[i];
  ushort4 o;
  o.x = f2bf(v.x); o.y = f2bf(v.y); o.z = f2bf(v.z); o.w = f2bf(v.w);
  ((ushort4*)out)[i] = o;
}

// ---------------------------------------------------------------------------
// gemm_bt: C[m][n] = sum_k A[m][k]*W[n][k] + bias[n]; 128x128 tile, 4 waves
// (2x2), 16x16x32 MFMA, global_load_lds staging into plane layout
// [kslot 0..3][row 0..127] (slot = 16B). Modes:
//   0: outf(fp32)+outb(bf16); 1: outb only; 2: outf = acc+bias+resid.
// ---------------------------------------------------------------------------
__global__ __launch_bounds__(256) void gemm_bt(
    const ushort* __restrict__ A, const ushort* __restrict__ W,
    const float* __restrict__ bias, int M, int N, int K, int mode,
    float* __restrict__ outf, ushort* __restrict__ outb,
    const float* __restrict__ resid) {
  __shared__ __align__(16) ushort sA[4096];   // 4 kslots * 128 rows * 8
  __shared__ __align__(16) ushort sB[4096];
  const int t = threadIdx.x, wave = t >> 6, lane = t & 63;
  const int c16 = lane & 15, quad = lane >> 4;
  const int wm = wave >> 1, wn = wave & 1;
  const int m0 = blockIdx.y * 128, n0 = blockIdx.x * 128;
  f32x4 acc[4][4] = {};
  // staging: call j=wave covers kslot=wave>>1, rows (wave&1)*64+lane;
  //          call j=wave+4 covers kslot+2, same rows
  const int rowa = (wave & 1) * 64 + lane;
  const int ks = wave >> 1;
  const ushort* gA0 = A + (size_t)(m0 + rowa) * K + ks * 8;
  const ushort* gA1 = gA0 + 16;                  // kslot+2 -> +16 ushorts
  const ushort* gB0 = W + (size_t)(n0 + rowa) * K + ks * 8;
  const ushort* gB1 = gB0 + 16;
  ushort* lA0 = sA + wave * 512;
  ushort* lA1 = sA + (wave + 4) * 512;
  ushort* lB0 = sB + wave * 512;
  ushort* lB1 = sB + (wave + 4) * 512;
  for (int k0 = 0; k0 < K; k0 += 32) {
    __syncthreads();
    glds16(gA0 + k0, lA0);
    glds16(gA1 + k0, lA1);
    glds16(gB0 + k0, lB0);
    glds16(gB1 + k0, lB1);
    __syncthreads();
    bf16x8 af[4], bfr[4];
#pragma unroll
    for (int i = 0; i < 4; ++i) {
      af[i]  = *(const bf16x8*)(sA + (quad * 128 + wm * 64 + i * 16 + c16) * 8);
      bfr[i] = *(const bf16x8*)(sB + (quad * 128 + wn * 64 + i * 16 + c16) * 8);
    }
#pragma unroll
    for (int mt = 0; mt < 4; ++mt)
#pragma unroll
      for (int nt = 0; nt < 4; ++nt)
        acc[mt][nt] = __builtin_amdgcn_mfma_f32_16x16x32_bf16(af[mt], bfr[nt],
                                                              acc[mt][nt], 0, 0, 0);
  }
  float bv[4];
#pragma unroll
  for (int nt = 0; nt < 4; ++nt) bv[nt] = bias[n0 + wn * 64 + nt * 16 + c16];
#pragma unroll
  for (int mt = 0; mt < 4; ++mt) {
#pragma unroll
    for (int nt = 0; nt < 4; ++nt) {
      const int n = n0 + wn * 64 + nt * 16 + c16;
#pragma unroll
      for (int r = 0; r < 4; ++r) {
        const int m = m0 + wm * 64 + mt * 16 + quad * 4 + r;
        const size_t idx = (size_t)m * N + n;
        float v = acc[mt][nt][r] + bv[nt];
        if (mode == 0)      { outf[idx] = v; outb[idx] = f2bf(v); }
        else if (mode == 1) { outb[idx] = f2bf(v); }
        else                { outf[idx] = v + resid[idx]; }
      }
    }
  }
}

// ---------------------------------------------------------------------------
// Vt transpose: vT[b][h][d][s] from qkv v-section (64x64 tiles via LDS).
// Each thread loads TWO rows (row, row+32) so the full 8KB tile is filled.
// ---------------------------------------------------------------------------
__global__ __launch_bounds__(256) void vtrans(const ushort* __restrict__ qkv,
                                              ushort* __restrict__ vt) {
  const int sb = blockIdx.x, h = blockIdx.y, b = blockIdx.z;
  __shared__ ushort tile[64][72];
  const int t = threadIdx.x;
  {
    const int row = t >> 3, c8 = (t & 7) * 8;   // row 0..31
    const ushort* src = qkv + (size_t)(b * 2048 + sb * 64 + row) * 3072 + 2048 + h * 64 + c8;
    *(uint4*)&tile[row][c8]      = *(const uint4*)src;
    *(uint4*)&tile[row + 32][c8] = *(const uint4*)(src + 32 * 3072);
  }
  __syncthreads();
  const int d = t >> 2, seg = (t & 3) * 16;
  unsigned wbuf[8];
#pragma unroll
  for (int i = 0; i < 8; ++i)
    wbuf[i] = (unsigned)tile[seg + 2 * i][d] | ((unsigned)tile[seg + 2 * i + 1][d] << 16);
  ushort* dst = vt + (size_t)((b * 16 + h) * 64 + d) * 2048 + sb * 64 + seg;
  *(uint4*)(dst)     = *(uint4*)&wbuf[0];
  *(uint4*)(dst + 8) = *(uint4*)&wbuf[4];
}

// ---------------------------------------------------------------------------
// Flash attention. Grid (S/128, H, B), 4 waves x 32 q-rows, KV tile 128.
//  S^T = K.Q^T  (A=K-frag, B=Q-frag) -> C[key][q], col q = lane&31.
//  O^T = V^T.P  (A=V-frag, B=P-frag) -> C[d][q]   (alpha/li lane-local).
// LDS: sK [dslot8][key128] plane; sV phi(d,ks)=d*16+(ks^(d&15));
//      sP per wave [q32][ks^(q&15)] swizzled. Total exactly 64KB.
// ---------------------------------------------------------------------------
__global__ __launch_bounds__(256) void attn_kernel(
    const ushort* __restrict__ qkv, const ushort* __restrict__ vtp,
    ushort* __restrict__ attn_out) {
  const int S = 2048;
  const int qblk = blockIdx.x, h = blockIdx.y, b = blockIdx.z;
  const int t = threadIdx.x, wave = t >> 6, lane = t & 63;
  const int c32 = lane & 31, hi = lane >> 5;
  __shared__ __align__(16) ushort sK[8192];          // 16 KB
  __shared__ __align__(16) ushort sV[8192];          // 16 KB
  __shared__ __align__(16) ushort sP[4][4096];       // 32 KB
  const int q0 = qblk * 128;
  const size_t qrow = (size_t)(b * S + q0 + wave * 32 + c32);
  // Q B-frags: Q[q=lane&31][d = dk*16 + hi*8 + j]
  bf16x8 qf[4];
  {
    const ushort* qp = qkv + qrow * 3072 + h * 64 + hi * 8;
#pragma unroll
    for (int dk = 0; dk < 4; ++dk) qf[dk] = *(const bf16x8*)(qp + dk * 16);
  }
  f32x16 o0 = {}, o1 = {};
  float mi = -1e30f, li = 0.f;
  const float k1 = 0.18033688011112042f;  // log2(e)/8
  ushort* sPw = &sP[wave][0];
  const int j0 = wave * 4;

  for (int kv0 = 0; kv0 < S; kv0 += 128) {
    __syncthreads();
#pragma unroll
    for (int c = 0; c < 4; ++c) {
      const int j = j0 + c;
      // sK: slot = dslot*128 + key
      const int dslot = j >> 1, key = (j & 1) * 64 + lane;
      glds16(qkv + (size_t)(b * S + kv0 + key) * 3072 + 1024 + h * 64 + dslot * 8,
             sK + j * 512);
      // sV: slot = d*16 + ks'; global ks = ks' ^ (d&15)
      const int d = j * 4 + (lane >> 4);
      const int ksv = (lane & 15) ^ (d & 15);
      glds16(vtp + (size_t)((b * 16 + h) * 64 + d) * S + kv0 + ksv * 8,
             sV + j * 512);
    }
    __syncthreads();
    // S^T tiles: sc[kt] covers keys kt*32.. ; C row=key-in-tile, col=q
    f32x16 sc[4];
#pragma unroll
    for (int kt = 0; kt < 4; ++kt) {
      f32x16 z = {};
#pragma unroll
      for (int dk = 0; dk < 4; ++dk) {
        bf16x8 kf = *(const bf16x8*)(sK + ((dk * 2 + hi) * 128 + kt * 32 + c32) * 8);
        z = __builtin_amdgcn_mfma_f32_32x32x16_bf16(kf, qf[dk], z, 0, 0, 0);
      }
      sc[kt] = z;
    }
    // online softmax in exp2 domain; all 64 lane-values share q = lane&31
    float mx = sc[0][0];
#pragma unroll
    for (int kt = 0; kt < 4; ++kt)
#pragma unroll
      for (int r = 0; r < 16; ++r) mx = fmaxf(mx, sc[kt][r]);
    mx = fmaxf(mx, __shfl_xor(mx, 32));
    const float mn = fmaxf(mi, mx * k1);
    const float alpha = EXP2(mi - mn);
    float sum = 0.f;
#pragma unroll
    for (int kt = 0; kt < 4; ++kt)
#pragma unroll
      for (int r = 0; r < 16; ++r) {
        const float p = EXP2(sc[kt][r] * k1 - mn);
        sc[kt][r] = p;
        sum += p;
      }
    sum += __shfl_xor(sum, 32);
    li = li * alpha + sum;
    mi = mn;
    o0 *= alpha;
    o1 *= alpha;
    // pack p (bf16 truncation via v_perm) and write P[q][key] (swizzled slots)
#pragma unroll
    for (int kt = 0; kt < 4; ++kt)
#pragma unroll
      for (int g = 0; g < 4; ++g) {
        uint2 w2;
        w2.x = __builtin_amdgcn_perm(__float_as_uint(sc[kt][g * 4 + 1]),
                                     __float_as_uint(sc[kt][g * 4 + 0]), 0x07060302u);
        w2.y = __builtin_amdgcn_perm(__float_as_uint(sc[kt][g * 4 + 3]),
                                     __float_as_uint(sc[kt][g * 4 + 2]), 0x07060302u);
        const int ksp = (kt * 4 + g) ^ (c32 & 15);
        *(uint2*)(sPw + c32 * 128 + ksp * 8 + hi * 4) = w2;
      }
    // O^T += V^T . P : 16 mfma; same-wave LDS RAW (DS pipe in-order per wave)
#pragma unroll
    for (int kc = 0; kc < 8; ++kc) {
      const int ksq = (kc * 2 + hi);
      bf16x8 pf = *(const bf16x8*)(sPw + c32 * 128 + (ksq ^ (c32 & 15)) * 8);
      bf16x8 vf0 = *(const bf16x8*)(sV + (c32 * 16 + (ksq ^ (c32 & 15))) * 8);
      o0 = __builtin_amdgcn_mfma_f32_32x32x16_bf16(vf0, pf, o0, 0, 0, 0);
      bf16x8 vf1 = *(const bf16x8*)(sV + ((32 + c32) * 16 + (ksq ^ (c32 & 15))) * 8);
      o1 = __builtin_amdgcn_mfma_f32_32x32x16_bf16(vf1, pf, o1, 0, 0, 0);
    }
  }
  // epilogue: O^T[d][q] -> attn[qrow][h*64+d], 8B packed stores
  const float inv = 1.f / li;
  ushort* orow = attn_out + qrow * 1024 + h * 64;
#pragma unroll
  for (int dt = 0; dt < 2; ++dt) {
    const f32x16 ov = dt ? o1 : o0;
#pragma unroll
    for (int g = 0; g < 4; ++g) {
      float v0 = ov[g * 4 + 0] * inv, v1 = ov[g * 4 + 1] * inv;
      float v2 = ov[g * 4 + 2] * inv, v3 = ov[g * 4 + 3] * inv;
      uint2 w2;
      w2.x = (unsigned)f2bf(v0) | ((unsigned)f2bf(v1) << 16);
      w2.y = (unsigned)f2bf(v2) | ((unsigned)f2bf(v3) << 16);
      *(uint2*)(orow + dt * 32 + g * 8 + hi * 4) = w2;
    }
  }
}

// ---------------------------------------------------------------------------
// LayerNorm over D=1024 per row.
// ---------------------------------------------------------------------------
__global__ __launch_bounds__(256) void ln_kernel(const float* __restrict__ y,
                                                 const float* __restrict__ g,
                                                 const float* __restrict__ bta,
                                                 float* __restrict__ out) {
  const int m = blockIdx.x;
  const int t = threadIdx.x;
  const float* row = y + (size_t)m * 1024;
  float4 v = ((const float4*)row)[t];
  float s = v.x + v.y + v.z + v.w;
  float s2 = v.x * v.x + v.y * v.y + v.z * v.z + v.w * v.w;
#pragma unroll
  for (int off = 1; off < 64; off <<= 1) {
    s += __shfl_xor(s, off, 64);
    s2 += __shfl_xor(s2, off, 64);
  }
  __shared__ float red[8];
  const int wave = t >> 6, lane = t & 63;
  if (lane == 0) { red[wave] = s; red[4 + wave] = s2; }
  __syncthreads();
  s = red[0] + red[1] + red[2] + red[3];
  s2 = red[4] + red[5] + red[6] + red[7];
  const float mu = s * (1.f / 1024.f);
  const float var = s2 * (1.f / 1024.f) - mu * mu;
  const float rs = rsqrtf(var + 1e-5f);
  float4 gg = ((const float4*)g)[t];
  float4 bb = ((const float4*)bta)[t];
  float4 o;
  o.x = (v.x - mu) * rs * gg.x + bb.x;
  o.y = (v.y - mu) * rs * gg.y + bb.y;
  o.z = (v.z - mu) * rs * gg.z + bb.z;
  o.w = (v.w - mu) * rs * gg.w + bb.w;
  ((float4*)(out + (size_t)m * 1024))[t] = o;
}

// ---------------------------------------------------------------------------
// Workspace (140 MB):
//  [0,48M)    qkvb bf16 [8192][3072]; also awin bf16 [0,32M) (dead before
//             phase3), and y fp32 [0,32M) in phase5 (qkvb dead after attn)
//  [48,80M)   chunkf fp32
//  [80,96M)   chunkb bf16
//  [96,112M)  vtb bf16 [B][H][64][S]
//  [112,128M) attnb bf16 [8192][1024]
//  [128,132M) cwb  [132,138M) ipwb  [138,140M) opwb
// ---------------------------------------------------------------------------
extern "C" void kernel_launch(void* const* d_in, const int* in_sizes, int n_in,
                              void* d_out, int out_size, void* d_ws, size_t ws_size,
                              hipStream_t stream) {
  const float* emb        = (const float*)d_in[0];
  const float* chunk_w    = (const float*)d_in[1];
  const float* chunk_b    = (const float*)d_in[2];
  const float* in_proj_w  = (const float*)d_in[3];
  const float* in_proj_b  = (const float*)d_in[4];
  const float* out_proj_w = (const float*)d_in[5];
  const float* out_proj_b = (const float*)d_in[6];
  const float* ln_g       = (const float*)d_in[7];
  const float* ln_b       = (const float*)d_in[8];

  char* w = (char*)d_ws;
  const size_t MBy = (size_t)1 << 20;
  ushort* qkvb  = (ushort*)(w + 0);
  ushort* awin  = (ushort*)(w + 0);            // dead before qkvb written
  float*  y     = (float*)(w + 0);             // dead after attn reads qkvb
  float*  chunkf = (float*)(w + 48 * MBy);
  ushort* chunkb = (ushort*)(w + 80 * MBy);
  ushort* vtb    = (ushort*)(w + 96 * MBy);
  ushort* attnb  = (ushort*)(w + 112 * MBy);
  ushort* cwb    = (ushort*)(w + 128 * MBy);
  ushort* ipwb   = (ushort*)(w + 132 * MBy);
  ushort* opwb   = (ushort*)(w + 138 * MBy);

  // Phase 1: bf16 conversions
  build_awin<<<16384, 256, 0, stream>>>(emb, awin);
  cvt_bf16<<<2048, 256, 0, stream>>>(chunk_w, cwb, 2 * 1024 * 1024 / 4);
  cvt_bf16<<<3072, 256, 0, stream>>>(in_proj_w, ipwb, 3 * 1024 * 1024 / 4);
  cvt_bf16<<<1024, 256, 0, stream>>>(out_proj_w, opwb, 1024 * 1024 / 4);

  // Phase 2: chunk = A_win @ chunk_w^T + b  (M=8192 N=1024 K=2048)
  gemm_bt<<<dim3(1024 / 128, 8192 / 128), 256, 0, stream>>>(
      awin, cwb, chunk_b, 8192, 1024, 2048, 0, chunkf, chunkb, nullptr);

  // Phase 3: qkv = chunk @ in_proj_w^T + b  (N=3072 K=1024), flat [m][3072]
  gemm_bt<<<dim3(3072 / 128, 8192 / 128), 256, 0, stream>>>(
      chunkb, ipwb, in_proj_b, 8192, 3072, 1024, 1, nullptr, qkvb, nullptr);

  // Phase 3b: v^T materialization
  vtrans<<<dim3(32, 16, 4), 256, 0, stream>>>(qkvb, vtb);

  // Phase 4: attention
  attn_kernel<<<dim3(2048 / 128, 16, 4), 256, 0, stream>>>(qkvb, vtb, attnb);

  // Phase 5: y = attn @ out_proj_w^T + b + chunk  (N=1024 K=1024)
  gemm_bt<<<dim3(1024 / 128, 8192 / 128), 256, 0, stream>>>(
      attnb, opwb, out_proj_b, 8192, 1024, 1024, 2, y, nullptr, chunkf);

  // Phase 6: LayerNorm -> d_out
  ln_kernel<<<8192, 256, 0, stream>>>(y, ln_g, ln_b, (float*)d_out);
}